// Round 1
// baseline (679.353 us; speedup 1.0000x reference)
//
#include <hip/hip_runtime.h>

typedef _Float16 f16x8 __attribute__((ext_vector_type(8)));
typedef float f32x4 __attribute__((ext_vector_type(4)));

#define NA 512
#define NB 512
#define NV 32
#define ND 512
#define NBV (NB * NV)  // 16384

// ---- K0: VT[b][d][v] (f16) from video[b][v][d] (fp32); one block per b ----
__global__ __launch_bounds__(256) void k_vt(const float* __restrict__ video,
                                            _Float16* __restrict__ vt) {
  __shared__ _Float16 tile[ND * NV];  // 32 KB, [d][v]
  int b = blockIdx.x, t = threadIdx.x;
  const float* vb = video + (size_t)b * NV * ND;
  int v = t >> 3, dc = (t & 7) * 64;
  for (int i = 0; i < 16; ++i) {
    f32x4 x = *(const f32x4*)(vb + v * ND + dc + i * 4);
    int d = dc + i * 4;
    tile[(d + 0) * NV + v] = (_Float16)x[0];
    tile[(d + 1) * NV + v] = (_Float16)x[1];
    tile[(d + 2) * NV + v] = (_Float16)x[2];
    tile[(d + 3) * NV + v] = (_Float16)x[3];
  }
  __syncthreads();
  f16x8* dst = (f16x8*)(vt + (size_t)b * ND * NV);
  const f16x8* src = (const f16x8*)tile;
  for (int i = 0; i < 8; ++i) dst[i * 256 + t] = src[i * 256 + t];
}

// convert 8 consecutive fp32 -> 8 f16, store 16B to LDS
__device__ inline void stage8(const float* __restrict__ g, _Float16* l) {
  f32x4 x = *(const f32x4*)g;
  f32x4 y = *(const f32x4*)(g + 4);
  f16x8 h;
  h[0] = (_Float16)x[0]; h[1] = (_Float16)x[1];
  h[2] = (_Float16)x[2]; h[3] = (_Float16)x[3];
  h[4] = (_Float16)y[0]; h[5] = (_Float16)y[1];
  h[6] = (_Float16)y[2]; h[7] = (_Float16)y[3];
  *(f16x8*)l = h;
}

// XOR-swizzled LDS offset: row-major [row][32 f16], chunk = 8 f16.
// Swizzle keeps both ds_write_b128 (staging) and ds_read_b128 (fragments)
// at 2-way bank aliasing (free) instead of 8-way.
__device__ inline int swz(int row, int ch) {
  return row * 32 + ((ch ^ ((row >> 1) & 3)) * 8);
}

// ---- K1: scores GEMM (f16 MFMA) + fused softmax over v -> W[a][b*32+v] f16
// M=512 (a), N=16384 (bv), K=512 (d). 128x128 tile, BK=32, 4 waves (2x2 of 64x64).
__global__ __launch_bounds__(256) void k_scores(const float* __restrict__ text,
                                                const float* __restrict__ video,
                                                _Float16* __restrict__ W) {
  __shared__ _Float16 As[128 * 32];  // 8 KB
  __shared__ _Float16 Bs[128 * 32];  // 8 KB
  int t = threadIdx.x;
  int m0 = blockIdx.y * 128, n0 = blockIdx.x * 128;
  int w = t >> 6, lane = t & 63, ln = lane & 15, q = lane >> 4;
  int wm = (w >> 1) * 64, wn = (w & 1) * 64;
  int r0 = t >> 2, c0 = t & 3;      // staging chunk t  (rows 0..63)
  int r1 = (t + 256) >> 2;          // staging chunk t+256 (rows 64..127), same c0
  f32x4 acc[4][4];
  for (int i = 0; i < 4; ++i)
    for (int j = 0; j < 4; ++j) acc[i][j] = (f32x4){0.f, 0.f, 0.f, 0.f};

  for (int kk = 0; kk < 16; ++kk) {
    int k0 = kk * 32;
    __syncthreads();
    stage8(text + (size_t)(m0 + r0) * ND + k0 + c0 * 8, As + swz(r0, c0));
    stage8(text + (size_t)(m0 + r1) * ND + k0 + c0 * 8, As + swz(r1, c0));
    stage8(video + (size_t)(n0 + r0) * ND + k0 + c0 * 8, Bs + swz(r0, c0));
    stage8(video + (size_t)(n0 + r1) * ND + k0 + c0 * 8, Bs + swz(r1, c0));
    __syncthreads();
    f16x8 af[4], bf[4];
    for (int mt = 0; mt < 4; ++mt)
      af[mt] = *(const f16x8*)(As + swz(wm + mt * 16 + ln, q));
    for (int nt = 0; nt < 4; ++nt)
      bf[nt] = *(const f16x8*)(Bs + swz(wn + nt * 16 + ln, q));
    for (int mt = 0; mt < 4; ++mt)
      for (int nt = 0; nt < 4; ++nt)
        acc[mt][nt] = __builtin_amdgcn_mfma_f32_16x16x32_f16(af[mt], bf[nt],
                                                             acc[mt][nt], 0, 0, 0);
  }

  // Softmax over each 32-col group (one b): cols g*32..g*32+31 = n-tiles {2g, 2g+1}.
  // C/D layout: row(m) = q*4+r, col(n) = ln. Row-reduce across 16 lanes (same q).
  const float invT = 0.2f;  // 1/TEMP
  for (int mt = 0; mt < 4; ++mt) {
    for (int g = 0; g < 2; ++g) {
      for (int r = 0; r < 4; ++r) {
        float v0 = acc[mt][2 * g][r] * invT;
        float v1 = acc[mt][2 * g + 1][r] * invT;
        float mx = fmaxf(v0, v1);
        for (int msk = 1; msk < 16; msk <<= 1)
          mx = fmaxf(mx, __shfl_xor(mx, msk, 16));
        float p0 = __expf(v0 - mx), p1 = __expf(v1 - mx);
        float s = p0 + p1;
        for (int msk = 1; msk < 16; msk <<= 1)
          s += __shfl_xor(s, msk, 16);
        float inv = 1.0f / s;
        int a = m0 + wm + mt * 16 + q * 4 + r;
        int col = n0 + wn + g * 32 + ln;
        W[(size_t)a * NBV + col] = (_Float16)(p0 * inv);
        W[(size_t)a * NBV + col + 16] = (_Float16)(p1 * inv);
      }
    }
  }
}

// ---- K2: out[a][b][d] = sum_v W[a][b*32+v] * video[b][v][d]; K=32 -> 1 MFMA/tile
// Block: one b, 64 a's, all 512 d (wave w covers d in [w*128, w*128+128)).
__global__ __launch_bounds__(256) void k_pool(const _Float16* __restrict__ W,
                                              const _Float16* __restrict__ vt,
                                              float* __restrict__ out) {
  int a0 = blockIdx.x * 64, b = blockIdx.y;
  int t = threadIdx.x, w = t >> 6, lane = t & 63, ln = lane & 15, q = lane >> 4;
  f16x8 af[4];
  for (int mt = 0; mt < 4; ++mt)
    af[mt] = *(const f16x8*)(W + (size_t)(a0 + mt * 16 + ln) * NBV + b * NV + q * 8);
  const _Float16* vtb = vt + (size_t)b * ND * NV;
  for (int nt = 0; nt < 8; ++nt) {
    int d0 = w * 128 + nt * 16;
    f16x8 bf = *(const f16x8*)(vtb + (d0 + ln) * NV + q * 8);
    for (int mt = 0; mt < 4; ++mt) {
      f32x4 c = (f32x4){0.f, 0.f, 0.f, 0.f};
      c = __builtin_amdgcn_mfma_f32_16x16x32_f16(af[mt], bf, c, 0, 0, 0);
      int abase = a0 + mt * 16 + q * 4;
      for (int r = 0; r < 4; ++r)
        out[((size_t)(abase + r) * NB + b) * ND + d0 + ln] = c[r];
    }
  }
}

extern "C" void kernel_launch(void* const* d_in, const int* in_sizes, int n_in,
                              void* d_out, int out_size, void* d_ws, size_t ws_size,
                              hipStream_t stream) {
  const float* text = (const float*)d_in[0];
  const float* video = (const float*)d_in[1];
  float* out = (float*)d_out;
  // workspace: VT (16 MB f16) + W (16 MB f16) = 32 MB
  _Float16* VT = (_Float16*)d_ws;
  _Float16* W = (_Float16*)((char*)d_ws + (size_t)NB * ND * NV * sizeof(_Float16));
  k_vt<<<dim3(NB), 256, 0, stream>>>(video, VT);
  k_scores<<<dim3(NBV / 128, NA / 128), 256, 0, stream>>>(text, video, W);
  k_pool<<<dim3(NA / 64, NB), 256, 0, stream>>>(W, VT, out);
}